// Round 3
// baseline (288.587 us; speedup 1.0000x reference)
//
#include <hip/hip_runtime.h>
#include <hip/hip_bf16.h>
#include <hip/hip_fp16.h>

typedef __attribute__((ext_vector_type(8))) short short8;     // bf16x8 frag
typedef __attribute__((ext_vector_type(8))) _Float16 half8;   // f16x8 frag
typedef __attribute__((ext_vector_type(4))) float f32x4;
typedef __attribute__((ext_vector_type(16))) float f32x16;
typedef __attribute__((ext_vector_type(4))) unsigned int uint4v;
typedef unsigned short u16;
typedef unsigned int u32;

#define LOG2E 1.44269504088896f

__device__ __forceinline__ u16 f2bf(float f) {
  u32 u = __builtin_bit_cast(u32, f);
  u += 0x7fffu + ((u >> 16) & 1u);
  return (u16)(u >> 16);
}
__device__ __forceinline__ u16 f2h(float f) {
  _Float16 h = (_Float16)f;
  return __builtin_bit_cast(u16, h);
}
__device__ __forceinline__ u32 cvtpk_bf16(float lo, float hi) {
  u32 r;
  asm("v_cvt_pk_bf16_f32 %0, %1, %2" : "=v"(r) : "v"(lo), "v"(hi));
  return r;
}

// ---------------------------------------------------------------------------
// K0: prep. xT[b][n][c] (f16) from x[b][c][n] (f32); W_all f16 [320][256]
// (rows 0-31 Wf, 32-63 Wg*LOG2E, 64-319 Wh); b_all f32 [320] (bg*LOG2E).
// ---------------------------------------------------------------------------
__global__ void k_prep(const float* __restrict__ x,
                       const float* __restrict__ Wf, const float* __restrict__ bfp,
                       const float* __restrict__ Wg, const float* __restrict__ bgp,
                       const float* __restrict__ Wh, const float* __restrict__ bhp,
                       u16* __restrict__ xT, u16* __restrict__ Wall,
                       float* __restrict__ ball)
{
  int bid = blockIdx.x, t = threadIdx.x;
  if (bid < 1024) {
    __shared__ u16 tile[64][68];
    int b = bid >> 8, c0 = ((bid >> 6) & 3) << 6, n0 = (bid & 63) << 6;
#pragma unroll
    for (int r = 0; r < 4; ++r) {
      int cl = (t >> 4) + r * 16, nl = (t & 15) * 4;
      const float4 v = *(const float4*)&x[(size_t)(b * 256 + c0 + cl) * 4096 + n0 + nl];
      tile[cl][nl + 0] = f2h(v.x); tile[cl][nl + 1] = f2h(v.y);
      tile[cl][nl + 2] = f2h(v.z); tile[cl][nl + 3] = f2h(v.w);
    }
    __syncthreads();
#pragma unroll
    for (int r = 0; r < 4; ++r) {
      int nl = (t >> 4) + r * 16, cl = (t & 15) * 4;
      ushort4 o;
      o.x = tile[cl + 0][nl]; o.y = tile[cl + 1][nl];
      o.z = tile[cl + 2][nl]; o.w = tile[cl + 3][nl];
      *(ushort4*)&xT[(size_t)(b * 4096 + n0 + nl) * 256 + c0 + cl] = o;
    }
  } else {
    int wb = bid - 1024;                 // 0..79
    int e = wb * 1024 + t * 4;           // element in W_all (320*256)
    int r = e >> 8;
    const float* src = (r < 32) ? (Wf + e)
                     : (r < 64) ? (Wg + e - 32 * 256)
                                : (Wh + e - 64 * 256);
    float4 v = *(const float4*)src;
    float sc = (r >= 32 && r < 64) ? LOG2E : 1.0f;   // pre-scale Q path
    ushort4 o;
    o.x = f2h(v.x * sc); o.y = f2h(v.y * sc);
    o.z = f2h(v.z * sc); o.w = f2h(v.w * sc);
    *(ushort4*)&Wall[e] = o;
    if (wb == 0 && t < 80) {
#pragma unroll
      for (int i = 0; i < 4; ++i) {
        int idx = t * 4 + i;
        ball[idx] = (idx < 32) ? bfp[idx]
                  : (idx < 64) ? bgp[idx - 32] * LOG2E
                               : bhp[idx - 64];
      }
    }
  }
}

// ---------------------------------------------------------------------------
// K1: projections via f16 MFMA (unchanged).
// ---------------------------------------------------------------------------
__global__ __launch_bounds__(256, 4)
void k_proj(const u16* __restrict__ xT, const u16* __restrict__ Wall,
            const float* __restrict__ ball,
            u16* __restrict__ q, u16* __restrict__ kmat, u16* __restrict__ hbf)
{
  int bid = blockIdx.x, t = threadIdx.x;
  int w = t >> 6, l = t & 63, lg = l >> 4, li = l & 15;
  f32x4 Z = {0.f, 0.f, 0.f, 0.f};
  if (bid < 256) {        // ---- FG ----
    int b = bid >> 6, n0 = (bid & 63) << 6;
    int rbase = w * 16;
    half8 aw[8];
#pragma unroll
    for (int kk = 0; kk < 8; ++kk)
      aw[kk] = *(const half8*)&Wall[(rbase + li) * 256 + kk * 32 + lg * 8];
    float bias[4];
#pragma unroll
    for (int j = 0; j < 4; ++j) bias[j] = ball[rbase + 4 * lg + j];
#pragma unroll
    for (int nn = 0; nn < 4; ++nn) {
      int n = n0 + nn * 16 + li;
      f32x4 acc = Z;
#pragma unroll
      for (int kk = 0; kk < 8; ++kk) {
        half8 bx = *(const half8*)&xT[(size_t)(b * 4096 + n) * 256 + kk * 32 + lg * 8];
        acc = __builtin_amdgcn_mfma_f32_16x16x32_f16(aw[kk], bx, acc, 0, 0, 0);
      }
      ushort4 o;
      o.x = f2h(acc[0] + bias[0]); o.y = f2h(acc[1] + bias[1]);
      o.z = f2h(acc[2] + bias[2]); o.w = f2h(acc[3] + bias[3]);
      u16* dst = (rbase < 32)
               ? (kmat + (size_t)(b * 4096 + n) * 32 + rbase + 4 * lg)
               : (q    + (size_t)(b * 4096 + n) * 32 + (rbase - 32) + 4 * lg);
      *(ushort4*)dst = o;
    }
  } else {                // ---- H ----
    int hb = bid - 256;
    int b = hb >> 8, rt = (hb >> 6) & 3, n0 = (hb & 63) << 6;
    int r0 = 64 + rt * 64;
    int nbase = n0 + w * 16;
    half8 ax[8];
#pragma unroll
    for (int kk = 0; kk < 8; ++kk)
      ax[kk] = *(const half8*)&xT[(size_t)(b * 4096 + nbase + li) * 256 + kk * 32 + lg * 8];
#pragma unroll
    for (int rr = 0; rr < 4; ++rr) {
      int r = r0 + rr * 16 + li;
      f32x4 acc = Z;
#pragma unroll
      for (int kk = 0; kk < 8; ++kk) {
        half8 bw = *(const half8*)&Wall[r * 256 + kk * 32 + lg * 8];
        acc = __builtin_amdgcn_mfma_f32_16x16x32_f16(ax[kk], bw, acc, 0, 0, 0);
      }
      float bias = ball[r];
      ushort4 o;
      o.x = f2bf(acc[0] + bias); o.y = f2bf(acc[1] + bias);
      o.z = f2bf(acc[2] + bias); o.w = f2bf(acc[3] + bias);
      *(ushort4*)&hbf[(size_t)(b * 256 + r - 64) * 4096 + nbase + 4 * lg] = o;
    }
  }
}

// ---------------------------------------------------------------------------
// K2 v3: swapped-S in-register attention, flat code, no spills.
//  8 waves: msub(2) x ch(2) x kh(2). Wave: 32 q x 128 c x 2048 keys.
//  Per 32-key step: V loads (distance-0) -> S = mfma32(K,Q) -> K prefetch
//  (distance-1) -> exp/pack in-register -> 8 PV mfma32.
//  acc in AGPRs (4 x f32x16); live VGPRs ~130. kh-merge via LDS at end.
// ---------------------------------------------------------------------------
__global__ __launch_bounds__(512, 2)
void k_attn(const u16* __restrict__ q, const u16* __restrict__ kmat,
            const u16* __restrict__ hbf, const float* __restrict__ xin,
            const float* __restrict__ gam, float* __restrict__ out)
{
  __shared__ float accL[4 * 64 * 64];   // 64 KB kh-merge
  __shared__ float vsL[64];
  __shared__ float invL[64];

  int bid = blockIdx.x, t = threadIdx.x;
  int xcd = bid & 7;
  int b = xcd >> 1;                         // batch pinned to 2 XCDs
  int mg = ((xcd & 1) << 5) | (bid >> 3);   // 0..63
  int m0 = mg << 6;
  int w = t >> 6, l = t & 63, l31 = l & 31, hi = l >> 5;
  int msub = w & 1, ch = (w >> 1) & 1, kh = w >> 2;
  int mb = m0 + msub * 32;
  int c0 = ch * 128;
  int nbase = kh * 2048;

  const u16* qb = q + (size_t)b * 4096 * 32;
  const u16* kb = kmat + (size_t)b * 4096 * 32;
  const u16* hb = hbf + (size_t)b * 256 * 4096;

  half8 qf0 = *(const half8*)&qb[(mb + l31) * 32 + hi * 8];
  half8 qf1 = *(const half8*)&qb[(mb + l31) * 32 + 16 + hi * 8];

  // per-ct V row base pointers (element units), column offset 4*hi baked in
  const u16* vp0 = hb + (size_t)(c0 +   0 + l31) * 4096 + 4 * hi;
  const u16* vp1 = hb + (size_t)(c0 +  32 + l31) * 4096 + 4 * hi;
  const u16* vp2 = hb + (size_t)(c0 +  64 + l31) * 4096 + 4 * hi;
  const u16* vp3 = hb + (size_t)(c0 +  96 + l31) * 4096 + 4 * hi;
  const u16* kp  = kb + (size_t)l31 * 32 + hi * 8;

  f32x16 Z16 = {0,0,0,0,0,0,0,0,0,0,0,0,0,0,0,0};
  f32x16 acc0 = Z16, acc1 = Z16, acc2 = Z16, acc3 = Z16;
  float vsum = 0.f;

  half8 k0 = *(const half8*)(kp + (size_t)nbase * 32);
  half8 k1 = *(const half8*)(kp + (size_t)nbase * 32 + 16);

  for (int it = 0; it < 64; ++it) {
    int n = nbase + it * 32;
    int nn = nbase + ((it * 32 + 32) & 2047);   // wrapped next (last is dummy)

    if ((it & 1) == 0) __builtin_amdgcn_s_barrier();   // pure rendezvous

    // ---- V loads for THIS step (covered by S + exp/pack below) ----
    uint2 a, b2;
    uint4v v00, v01, v10, v11, v20, v21, v30, v31;
    a = *(const uint2*)(vp0 + n);      b2 = *(const uint2*)(vp0 + n + 8);
    v00 = (uint4v){a.x, a.y, b2.x, b2.y};
    a = *(const uint2*)(vp0 + n + 16); b2 = *(const uint2*)(vp0 + n + 24);
    v01 = (uint4v){a.x, a.y, b2.x, b2.y};
    a = *(const uint2*)(vp1 + n);      b2 = *(const uint2*)(vp1 + n + 8);
    v10 = (uint4v){a.x, a.y, b2.x, b2.y};
    a = *(const uint2*)(vp1 + n + 16); b2 = *(const uint2*)(vp1 + n + 24);
    v11 = (uint4v){a.x, a.y, b2.x, b2.y};
    a = *(const uint2*)(vp2 + n);      b2 = *(const uint2*)(vp2 + n + 8);
    v20 = (uint4v){a.x, a.y, b2.x, b2.y};
    a = *(const uint2*)(vp2 + n + 16); b2 = *(const uint2*)(vp2 + n + 24);
    v21 = (uint4v){a.x, a.y, b2.x, b2.y};
    a = *(const uint2*)(vp3 + n);      b2 = *(const uint2*)(vp3 + n + 8);
    v30 = (uint4v){a.x, a.y, b2.x, b2.y};
    a = *(const uint2*)(vp3 + n + 16); b2 = *(const uint2*)(vp3 + n + 24);
    v31 = (uint4v){a.x, a.y, b2.x, b2.y};

    // ---- S = K * Q (swapped): lane holds P[n-rows][m = l31] ----
    f32x16 sa = __builtin_amdgcn_mfma_f32_32x32x16_f16(k0, qf0, Z16, 0, 0, 0);
    sa = __builtin_amdgcn_mfma_f32_32x32x16_f16(k1, qf1, sa, 0, 0, 0);

    // ---- K prefetch (distance-1) ----
    k0 = *(const half8*)(kp + (size_t)nn * 32);
    k1 = *(const half8*)(kp + (size_t)nn * 32 + 16);

    // ---- exp + row-sum + pack to bf16 ----
    float p[16];
#pragma unroll
    for (int r = 0; r < 16; ++r) p[r] = __builtin_amdgcn_exp2f(sa[r]);
    float s0 = 0.f, s1 = 0.f;
#pragma unroll
    for (int r = 0; r < 16; r += 2) { s0 += p[r]; s1 += p[r + 1]; }
    vsum += s0 + s1;
    u32 pk[8];
#pragma unroll
    for (int i = 0; i < 8; ++i) pk[i] = cvtpk_bf16(p[2 * i], p[2 * i + 1]);
    uint4v a0 = {pk[0], pk[1], pk[2], pk[3]};
    uint4v a1 = {pk[4], pk[5], pk[6], pk[7]};
    short8 pa0 = __builtin_bit_cast(short8, a0);
    short8 pa1 = __builtin_bit_cast(short8, a1);

    // ---- PV: 8 x mfma32x32x16 bf16 ----
    __builtin_amdgcn_s_setprio(1);
    acc0 = __builtin_amdgcn_mfma_f32_32x32x16_bf16(pa0, __builtin_bit_cast(short8, v00), acc0, 0, 0, 0);
    acc0 = __builtin_amdgcn_mfma_f32_32x32x16_bf16(pa1, __builtin_bit_cast(short8, v01), acc0, 0, 0, 0);
    acc1 = __builtin_amdgcn_mfma_f32_32x32x16_bf16(pa0, __builtin_bit_cast(short8, v10), acc1, 0, 0, 0);
    acc1 = __builtin_amdgcn_mfma_f32_32x32x16_bf16(pa1, __builtin_bit_cast(short8, v11), acc1, 0, 0, 0);
    acc2 = __builtin_amdgcn_mfma_f32_32x32x16_bf16(pa0, __builtin_bit_cast(short8, v20), acc2, 0, 0, 0);
    acc2 = __builtin_amdgcn_mfma_f32_32x32x16_bf16(pa1, __builtin_bit_cast(short8, v21), acc2, 0, 0, 0);
    acc3 = __builtin_amdgcn_mfma_f32_32x32x16_bf16(pa0, __builtin_bit_cast(short8, v30), acc3, 0, 0, 0);
    acc3 = __builtin_amdgcn_mfma_f32_32x32x16_bf16(pa1, __builtin_bit_cast(short8, v31), acc3, 0, 0, 0);
    __builtin_amdgcn_s_setprio(0);
  }

  // ---- epilogue: kh-merge + normalize + write (validated in R1) ----
  f32x16 acc[4] = {acc0, acc1, acc2, acc3};
  float vt = vsum + __shfl_xor(vsum, 32);
  int region = w & 3;
  if (kh == 1) {
#pragma unroll
    for (int ct = 0; ct < 4; ++ct)
#pragma unroll
      for (int g = 0; g < 4; ++g) {
        int j4 = ct * 4 + g;
        float4 v4 = {acc[ct][4 * g], acc[ct][4 * g + 1],
                     acc[ct][4 * g + 2], acc[ct][4 * g + 3]};
        *(float4*)&accL[region * 4096 + l * 64 + ((j4 ^ (l & 15)) * 4)] = v4;
      }
    if (ch == 0 && l < 32) vsL[msub * 32 + l31] = vt;
  }
  __syncthreads();
  if (kh == 0) {
#pragma unroll
    for (int ct = 0; ct < 4; ++ct)
#pragma unroll
      for (int g = 0; g < 4; ++g) {
        int j4 = ct * 4 + g;
        float4 v4 = *(const float4*)&accL[region * 4096 + l * 64 + ((j4 ^ (l & 15)) * 4)];
        acc[ct][4 * g] += v4.x; acc[ct][4 * g + 1] += v4.y;
        acc[ct][4 * g + 2] += v4.z; acc[ct][4 * g + 3] += v4.w;
      }
    if (ch == 0 && l < 32)
      invL[msub * 32 + l31] = 1.0f / (vt + vsL[msub * 32 + l31]);
  }
  __syncthreads();
  if (kh == 0) {
    float gamma = gam[0];
    const float* xb = xin + (size_t)b * 256 * 4096;
    float* ob = out + (size_t)b * 256 * 4096;
#pragma unroll
    for (int g = 0; g < 4; ++g) {
      float4 inv4 = *(const float4*)&invL[msub * 32 + 8 * g + 4 * hi];
#pragma unroll
      for (int ct = 0; ct < 4; ++ct) {
        int c = c0 + ct * 32 + l31;
        size_t base = (size_t)c * 4096 + mb + 8 * g + 4 * hi;
        float4 xv = *(const float4*)&xb[base];
        float4 ov;
        ov.x = gamma * acc[ct][4 * g + 0] * inv4.x + xv.x;
        ov.y = gamma * acc[ct][4 * g + 1] * inv4.y + xv.y;
        ov.z = gamma * acc[ct][4 * g + 2] * inv4.z + xv.z;
        ov.w = gamma * acc[ct][4 * g + 3] * inv4.w + xv.w;
        *(float4*)&ob[base] = ov;
      }
    }
  }
}

// ---------------------------------------------------------------------------
extern "C" void kernel_launch(void* const* d_in, const int* in_sizes, int n_in,
                              void* d_out, int out_size, void* d_ws, size_t ws_size,
                              hipStream_t stream)
{
  const float* x   = (const float*)d_in[0];
  const float* Wf  = (const float*)d_in[1];
  const float* bfp = (const float*)d_in[2];
  const float* Wg  = (const float*)d_in[3];
  const float* bgp = (const float*)d_in[4];
  const float* Wh  = (const float*)d_in[5];
  const float* bhp = (const float*)d_in[6];
  const float* gam = (const float*)d_in[7];
  float* out = (float*)d_out;

  char* ws = (char*)d_ws;
  u16*   xT   = (u16*)(ws);                  // 8,388,608 B  f16 [4][4096][256]
  u16*   Wall = (u16*)(ws + 8388608);        //   163,840 B  f16 [320][256]
  float* ball = (float*)(ws + 8552448);      //     2,048 B  f32 [320]
  u16*   q    = (u16*)(ws + 8554496);        // 2,097,152 B  f16 [4][4096][32]  (g, *log2e)
  u16*   km   = (u16*)(ws + 10651648);       // 2,097,152 B  f16 [4][4096][32]  (f)
  u16*   hbf  = (u16*)(ws + 12748800);       // 8,388,608 B  bf16 [4][256][4096] (h)

  k_prep<<<dim3(1104), dim3(256), 0, stream>>>(x, Wf, bfp, Wg, bgp, Wh, bhp, xT, Wall, ball);
  k_proj<<<dim3(1280), dim3(256), 0, stream>>>(xT, Wall, ball, q, km, hbf);
  k_attn<<<dim3(256),  dim3(512), 0, stream>>>(q, km, hbf, x, gam, out);
}

// Round 4
// 136.811 us; speedup vs baseline: 2.1094x; 2.1094x over previous
//
#include <hip/hip_runtime.h>
#include <hip/hip_bf16.h>
#include <hip/hip_fp16.h>

typedef __attribute__((ext_vector_type(8))) short short8;     // bf16x8 frag
typedef __attribute__((ext_vector_type(8))) _Float16 half8;   // f16x8 frag
typedef __attribute__((ext_vector_type(4))) float f32x4;
typedef __attribute__((ext_vector_type(16))) float f32x16;
typedef __attribute__((ext_vector_type(4))) unsigned int uint4v;
typedef unsigned short u16;
typedef unsigned int u32;

#define LOG2E 1.44269504088896f

typedef const void __attribute__((address_space(1))) gvoid;
typedef void __attribute__((address_space(3))) lvoid;

__device__ __forceinline__ void gll16(const void* g, void* l) {
  __builtin_amdgcn_global_load_lds((gvoid*)g, (lvoid*)l, 16, 0, 0);
}

__device__ __forceinline__ u16 f2bf(float f) {
  u32 u = __builtin_bit_cast(u32, f);
  u += 0x7fffu + ((u >> 16) & 1u);
  return (u16)(u >> 16);
}
__device__ __forceinline__ u16 f2h(float f) {
  _Float16 h = (_Float16)f;
  return __builtin_bit_cast(u16, h);
}
__device__ __forceinline__ u32 cvtpk_bf16(float lo, float hi) {
  u32 r;
  asm("v_cvt_pk_bf16_f32 %0, %1, %2" : "=v"(r) : "v"(lo), "v"(hi));
  return r;
}

// ---------------------------------------------------------------------------
// K0: prep. xT[b][n][c] (f16) from x[b][c][n] (f32); W_all f16 [320][256]
// (rows 0-31 Wf, 32-63 Wg*LOG2E, 64-319 Wh); b_all f32 [320] (bg*LOG2E).
// ---------------------------------------------------------------------------
__global__ void k_prep(const float* __restrict__ x,
                       const float* __restrict__ Wf, const float* __restrict__ bfp,
                       const float* __restrict__ Wg, const float* __restrict__ bgp,
                       const float* __restrict__ Wh, const float* __restrict__ bhp,
                       u16* __restrict__ xT, u16* __restrict__ Wall,
                       float* __restrict__ ball)
{
  int bid = blockIdx.x, t = threadIdx.x;
  if (bid < 1024) {
    __shared__ u16 tile[64][68];
    int b = bid >> 8, c0 = ((bid >> 6) & 3) << 6, n0 = (bid & 63) << 6;
#pragma unroll
    for (int r = 0; r < 4; ++r) {
      int cl = (t >> 4) + r * 16, nl = (t & 15) * 4;
      const float4 v = *(const float4*)&x[(size_t)(b * 256 + c0 + cl) * 4096 + n0 + nl];
      tile[cl][nl + 0] = f2h(v.x); tile[cl][nl + 1] = f2h(v.y);
      tile[cl][nl + 2] = f2h(v.z); tile[cl][nl + 3] = f2h(v.w);
    }
    __syncthreads();
#pragma unroll
    for (int r = 0; r < 4; ++r) {
      int nl = (t >> 4) + r * 16, cl = (t & 15) * 4;
      ushort4 o;
      o.x = tile[cl + 0][nl]; o.y = tile[cl + 1][nl];
      o.z = tile[cl + 2][nl]; o.w = tile[cl + 3][nl];
      *(ushort4*)&xT[(size_t)(b * 4096 + n0 + nl) * 256 + c0 + cl] = o;
    }
  } else {
    int wb = bid - 1024;                 // 0..79
    int e = wb * 1024 + t * 4;           // element in W_all (320*256)
    int r = e >> 8;
    const float* src = (r < 32) ? (Wf + e)
                     : (r < 64) ? (Wg + e - 32 * 256)
                                : (Wh + e - 64 * 256);
    float4 v = *(const float4*)src;
    float sc = (r >= 32 && r < 64) ? LOG2E : 1.0f;   // pre-scale Q path
    ushort4 o;
    o.x = f2h(v.x * sc); o.y = f2h(v.y * sc);
    o.z = f2h(v.z * sc); o.w = f2h(v.w * sc);
    *(ushort4*)&Wall[e] = o;
    if (wb == 0 && t < 80) {
#pragma unroll
      for (int i = 0; i < 4; ++i) {
        int idx = t * 4 + i;
        ball[idx] = (idx < 32) ? bfp[idx]
                  : (idx < 64) ? bgp[idx - 32] * LOG2E
                               : bhp[idx - 64];
      }
    }
  }
}

// ---------------------------------------------------------------------------
// K1: projections via f16 MFMA (unchanged).
// ---------------------------------------------------------------------------
__global__ __launch_bounds__(256, 4)
void k_proj(const u16* __restrict__ xT, const u16* __restrict__ Wall,
            const float* __restrict__ ball,
            u16* __restrict__ q, u16* __restrict__ kmat, u16* __restrict__ hbf)
{
  int bid = blockIdx.x, t = threadIdx.x;
  int w = t >> 6, l = t & 63, lg = l >> 4, li = l & 15;
  f32x4 Z = {0.f, 0.f, 0.f, 0.f};
  if (bid < 256) {        // ---- FG ----
    int b = bid >> 6, n0 = (bid & 63) << 6;
    int rbase = w * 16;
    half8 aw[8];
#pragma unroll
    for (int kk = 0; kk < 8; ++kk)
      aw[kk] = *(const half8*)&Wall[(rbase + li) * 256 + kk * 32 + lg * 8];
    float bias[4];
#pragma unroll
    for (int j = 0; j < 4; ++j) bias[j] = ball[rbase + 4 * lg + j];
#pragma unroll
    for (int nn = 0; nn < 4; ++nn) {
      int n = n0 + nn * 16 + li;
      f32x4 acc = Z;
#pragma unroll
      for (int kk = 0; kk < 8; ++kk) {
        half8 bx = *(const half8*)&xT[(size_t)(b * 4096 + n) * 256 + kk * 32 + lg * 8];
        acc = __builtin_amdgcn_mfma_f32_16x16x32_f16(aw[kk], bx, acc, 0, 0, 0);
      }
      ushort4 o;
      o.x = f2h(acc[0] + bias[0]); o.y = f2h(acc[1] + bias[1]);
      o.z = f2h(acc[2] + bias[2]); o.w = f2h(acc[3] + bias[3]);
      u16* dst = (rbase < 32)
               ? (kmat + (size_t)(b * 4096 + n) * 32 + rbase + 4 * lg)
               : (q    + (size_t)(b * 4096 + n) * 32 + (rbase - 32) + 4 * lg);
      *(ushort4*)dst = o;
    }
  } else {                // ---- H ----
    int hb = bid - 256;
    int b = hb >> 8, rt = (hb >> 6) & 3, n0 = (hb & 63) << 6;
    int r0 = 64 + rt * 64;
    int nbase = n0 + w * 16;
    half8 ax[8];
#pragma unroll
    for (int kk = 0; kk < 8; ++kk)
      ax[kk] = *(const half8*)&xT[(size_t)(b * 4096 + nbase + li) * 256 + kk * 32 + lg * 8];
#pragma unroll
    for (int rr = 0; rr < 4; ++rr) {
      int r = r0 + rr * 16 + li;
      f32x4 acc = Z;
#pragma unroll
      for (int kk = 0; kk < 8; ++kk) {
        half8 bw = *(const half8*)&Wall[r * 256 + kk * 32 + lg * 8];
        acc = __builtin_amdgcn_mfma_f32_16x16x32_f16(ax[kk], bw, acc, 0, 0, 0);
      }
      float bias = ball[r];
      ushort4 o;
      o.x = f2bf(acc[0] + bias); o.y = f2bf(acc[1] + bias);
      o.z = f2bf(acc[2] + bias); o.w = f2bf(acc[3] + bias);
      *(ushort4*)&hbf[(size_t)(b * 256 + r - 64) * 4096 + nbase + 4 * lg] = o;
    }
  }
}

// ---------------------------------------------------------------------------
// K2 v4: LDS-staged swapped-S attention.
//  8 waves: msub(2) x ch(2) x kh(2). Per 32-key step:
//   - stage next K (4KB) + V (32KB) tiles via global_load_lds (coalesced,
//     16B-chunk XOR swizzle applied on the GLOBAL source; LDS dest linear)
//   - one __syncthreads per step (its vmcnt(0) drain lands prev staging)
//   - frags read from LDS (swizzled reads = bank-floor), math identical to R2.
//  LDS: V 2x2x256x32 (64KB) + K 2x2x32x32 (8KB); epilogue accL overlays V.
// ---------------------------------------------------------------------------
__global__ __launch_bounds__(512, 1)
void k_attn(const u16* __restrict__ q, const u16* __restrict__ kmat,
            const u16* __restrict__ hbf, const float* __restrict__ xin,
            const float* __restrict__ gam, float* __restrict__ out)
{
  __shared__ __align__(16) char raw[74240];
  // V:   [0, 65536)   = [buf2][kh2][c256][32 u16]
  // K:   [65536,73728) = [buf2][kh2][row32][32 u16]
  // vsL: [73728,73984) invL: [73984,74240)
  float* vsL  = (float*)(raw + 73728);
  float* invL = (float*)(raw + 73984);

  int bid = blockIdx.x, t = threadIdx.x;
  int xcd = bid & 7;
  int b = xcd >> 1;                         // batch pinned to 2 XCDs
  int mg = ((xcd & 1) << 5) | (bid >> 3);   // 0..63
  int m0 = mg << 6;
  int w = t >> 6, l = t & 63, l31 = l & 31, hi = l >> 5;
  int msub = w & 1, ch = (w >> 1) & 1, kh = w >> 2;
  int mb = m0 + msub * 32;
  int c0 = ch * 128;

  const u16* qb = q + (size_t)b * 4096 * 32;
  const u16* kb = kmat + (size_t)b * 4096 * 32;
  const u16* hb = hbf + (size_t)b * 256 * 4096;

  half8 qf0 = *(const half8*)&qb[(mb + l31) * 32 + hi * 8];
  half8 qf1 = *(const half8*)&qb[(mb + l31) * 32 + 16 + hi * 8];

  f32x16 Z16 = {0,0,0,0,0,0,0,0,0,0,0,0,0,0,0,0};
  f32x16 acc0 = Z16, acc1 = Z16, acc2 = Z16, acc3 = Z16;
  float vsum = 0.f;

  // --- staging helpers (all index math in registers, wave-uniform dests) ---
  int wq = t & ~63;   // wave base thread

  // prologue: stage tile 0 into buf 0
  {
    int nt0 = 0;
#pragma unroll
    for (int i = 0; i < 4; ++i) {
      int u = i * 512 + t;
      int skh = u >> 10, sc = (u >> 2) & 255, qp = u & 3;
      int qg = qp ^ ((sc >> 1) & 3);
      const u16* src = hb + (size_t)sc * 4096 + skh * 2048 + nt0 + qg * 8;
      char* dst = raw + (i * 512 + wq) * 16;
      gll16(src, dst);
    }
    if (w < 4) {
      int u = t;                 // 0..255
      int skh = u >> 7, row = (u >> 2) & 31, qp = u & 3;
      int qg = qp ^ (row & 3);
      const u16* src = kb + (size_t)(skh * 2048 + nt0 + row) * 32 + qg * 8;
      char* dst = raw + 65536 + wq * 16;
      gll16(src, dst);
    }
  }

  // per-lane read bases
  int khV = kh * 16384;      // byte offset of my kh V-tile within a buf
  int khK = kh * 2048;

  for (int it = 0; it < 64; ++it) {
    int buf = it & 1;
    __syncthreads();           // drains vmcnt(0): cur tile staged; prev reads done

    // ---- stage NEXT tile into buf^1 (lands during this step's compute) ----
    if (it < 63) {
      int ntn = (it + 1) * 32;
      int bufn = buf ^ 1;
#pragma unroll
      for (int i = 0; i < 4; ++i) {
        int u = i * 512 + t;
        int skh = u >> 10, sc = (u >> 2) & 255, qp = u & 3;
        int qg = qp ^ ((sc >> 1) & 3);
        const u16* src = hb + (size_t)sc * 4096 + skh * 2048 + ntn + qg * 8;
        char* dst = raw + bufn * 32768 + (i * 512 + wq) * 16;
        gll16(src, dst);
      }
      if (w < 4) {
        int u = t;
        int skh = u >> 7, row = (u >> 2) & 31, qp = u & 3;
        int qg = qp ^ (row & 3);
        const u16* src = kb + (size_t)(skh * 2048 + ntn + row) * 32 + qg * 8;
        char* dst = raw + 65536 + bufn * 4096 + wq * 16;
        gll16(src, dst);
      }
    }

    // ---- K frags from LDS (chunk swizzle ^ (row&3)) ----
    const char* kr = raw + 65536 + buf * 4096 + khK + l31 * 64;
    int sk = (l31 & 3) * 16;
    half8 k0 = *(const half8*)(kr + ((hi * 16) ^ sk));
    half8 k1 = *(const half8*)(kr + ((32 + hi * 16) ^ sk));

    // ---- S = K * Q (swapped): lane holds P[n-rows][m = l31] ----
    f32x16 sa = __builtin_amdgcn_mfma_f32_32x32x16_f16(k0, qf0, Z16, 0, 0, 0);
    sa = __builtin_amdgcn_mfma_f32_32x32x16_f16(k1, qf1, sa, 0, 0, 0);

    // ---- V frags from LDS (8B slot swizzle ^ ((c>>1)&3)<<1) ----
    const char* vbase = raw + buf * 32768 + khV;
    uint2 a0, a1;
    uint4v v00, v01, v10, v11, v20, v21, v30, v31;
    {
      const char* vr = vbase + (c0 + 0 + l31) * 64;
      int sv = (((c0 + 0 + l31) >> 1) & 3) << 1;
      a0 = *(const uint2*)(vr + ((0 + hi) ^ sv) * 8);
      a1 = *(const uint2*)(vr + ((2 + hi) ^ sv) * 8);
      v00 = (uint4v){a0.x, a0.y, a1.x, a1.y};
      a0 = *(const uint2*)(vr + ((4 + hi) ^ sv) * 8);
      a1 = *(const uint2*)(vr + ((6 + hi) ^ sv) * 8);
      v01 = (uint4v){a0.x, a0.y, a1.x, a1.y};
    }
    {
      const char* vr = vbase + (c0 + 32 + l31) * 64;
      int sv = (((c0 + 32 + l31) >> 1) & 3) << 1;
      a0 = *(const uint2*)(vr + ((0 + hi) ^ sv) * 8);
      a1 = *(const uint2*)(vr + ((2 + hi) ^ sv) * 8);
      v10 = (uint4v){a0.x, a0.y, a1.x, a1.y};
      a0 = *(const uint2*)(vr + ((4 + hi) ^ sv) * 8);
      a1 = *(const uint2*)(vr + ((6 + hi) ^ sv) * 8);
      v11 = (uint4v){a0.x, a0.y, a1.x, a1.y};
    }
    {
      const char* vr = vbase + (c0 + 64 + l31) * 64;
      int sv = (((c0 + 64 + l31) >> 1) & 3) << 1;
      a0 = *(const uint2*)(vr + ((0 + hi) ^ sv) * 8);
      a1 = *(const uint2*)(vr + ((2 + hi) ^ sv) * 8);
      v20 = (uint4v){a0.x, a0.y, a1.x, a1.y};
      a0 = *(const uint2*)(vr + ((4 + hi) ^ sv) * 8);
      a1 = *(const uint2*)(vr + ((6 + hi) ^ sv) * 8);
      v21 = (uint4v){a0.x, a0.y, a1.x, a1.y};
    }
    {
      const char* vr = vbase + (c0 + 96 + l31) * 64;
      int sv = (((c0 + 96 + l31) >> 1) & 3) << 1;
      a0 = *(const uint2*)(vr + ((0 + hi) ^ sv) * 8);
      a1 = *(const uint2*)(vr + ((2 + hi) ^ sv) * 8);
      v30 = (uint4v){a0.x, a0.y, a1.x, a1.y};
      a0 = *(const uint2*)(vr + ((4 + hi) ^ sv) * 8);
      a1 = *(const uint2*)(vr + ((6 + hi) ^ sv) * 8);
      v31 = (uint4v){a0.x, a0.y, a1.x, a1.y};
    }

    // ---- exp + row-sum + pack to bf16 ----
    float p[16];
#pragma unroll
    for (int r = 0; r < 16; ++r) p[r] = __builtin_amdgcn_exp2f(sa[r]);
    float s0 = 0.f, s1 = 0.f;
#pragma unroll
    for (int r = 0; r < 16; r += 2) { s0 += p[r]; s1 += p[r + 1]; }
    vsum += s0 + s1;
    u32 pk[8];
#pragma unroll
    for (int i = 0; i < 8; ++i) pk[i] = cvtpk_bf16(p[2 * i], p[2 * i + 1]);
    uint4v pa0u = {pk[0], pk[1], pk[2], pk[3]};
    uint4v pa1u = {pk[4], pk[5], pk[6], pk[7]};
    short8 pa0 = __builtin_bit_cast(short8, pa0u);
    short8 pa1 = __builtin_bit_cast(short8, pa1u);

    // ---- PV: 8 x mfma32x32x16 bf16 ----
    __builtin_amdgcn_s_setprio(1);
    acc0 = __builtin_amdgcn_mfma_f32_32x32x16_bf16(pa0, __builtin_bit_cast(short8, v00), acc0, 0, 0, 0);
    acc0 = __builtin_amdgcn_mfma_f32_32x32x16_bf16(pa1, __builtin_bit_cast(short8, v01), acc0, 0, 0, 0);
    acc1 = __builtin_amdgcn_mfma_f32_32x32x16_bf16(pa0, __builtin_bit_cast(short8, v10), acc1, 0, 0, 0);
    acc1 = __builtin_amdgcn_mfma_f32_32x32x16_bf16(pa1, __builtin_bit_cast(short8, v11), acc1, 0, 0, 0);
    acc2 = __builtin_amdgcn_mfma_f32_32x32x16_bf16(pa0, __builtin_bit_cast(short8, v20), acc2, 0, 0, 0);
    acc2 = __builtin_amdgcn_mfma_f32_32x32x16_bf16(pa1, __builtin_bit_cast(short8, v21), acc2, 0, 0, 0);
    acc3 = __builtin_amdgcn_mfma_f32_32x32x16_bf16(pa0, __builtin_bit_cast(short8, v30), acc3, 0, 0, 0);
    acc3 = __builtin_amdgcn_mfma_f32_32x32x16_bf16(pa1, __builtin_bit_cast(short8, v31), acc3, 0, 0, 0);
    __builtin_amdgcn_s_setprio(0);
  }

  // ---- epilogue: kh-merge + normalize + write (accL overlays V buffers) ----
  __syncthreads();                       // all loop reads done before overwrite
  float* accL = (float*)raw;
  f32x16 acc[4] = {acc0, acc1, acc2, acc3};
  float vt = vsum + __shfl_xor(vsum, 32);
  int region = w & 3;
  if (kh == 1) {
#pragma unroll
    for (int ct = 0; ct < 4; ++ct)
#pragma unroll
      for (int g = 0; g < 4; ++g) {
        int j4 = ct * 4 + g;
        float4 v4 = {acc[ct][4 * g], acc[ct][4 * g + 1],
                     acc[ct][4 * g + 2], acc[ct][4 * g + 3]};
        *(float4*)&accL[region * 4096 + l * 64 + ((j4 ^ (l & 15)) * 4)] = v4;
      }
    if (ch == 0 && l < 32) vsL[msub * 32 + l31] = vt;
  }
  __syncthreads();
  if (kh == 0) {
#pragma unroll
    for (int ct = 0; ct < 4; ++ct)
#pragma unroll
      for (int g = 0; g < 4; ++g) {
        int j4 = ct * 4 + g;
        float4 v4 = *(const float4*)&accL[region * 4096 + l * 64 + ((j4 ^ (l & 15)) * 4)];
        acc[ct][4 * g] += v4.x; acc[ct][4 * g + 1] += v4.y;
        acc[ct][4 * g + 2] += v4.z; acc[ct][4 * g + 3] += v4.w;
      }
    if (ch == 0 && l < 32)
      invL[msub * 32 + l31] = 1.0f / (vt + vsL[msub * 32 + l31]);
  }
  __syncthreads();
  if (kh == 0) {
    float gamma = gam[0];
    const float* xb = xin + (size_t)b * 256 * 4096;
    float* ob = out + (size_t)b * 256 * 4096;
#pragma unroll
    for (int g = 0; g < 4; ++g) {
      float4 inv4 = *(const float4*)&invL[msub * 32 + 8 * g + 4 * hi];
#pragma unroll
      for (int ct = 0; ct < 4; ++ct) {
        int c = c0 + ct * 32 + l31;
        size_t base = (size_t)c * 4096 + mb + 8 * g + 4 * hi;
        float4 xv = *(const float4*)&xb[base];
        float4 ov;
        ov.x = gamma * acc[ct][4 * g + 0] * inv4.x + xv.x;
        ov.y = gamma * acc[ct][4 * g + 1] * inv4.y + xv.y;
        ov.z = gamma * acc[ct][4 * g + 2] * inv4.z + xv.z;
        ov.w = gamma * acc[ct][4 * g + 3] * inv4.w + xv.w;
        *(float4*)&ob[base] = ov;
      }
    }
  }
}

// ---------------------------------------------------------------------------
extern "C" void kernel_launch(void* const* d_in, const int* in_sizes, int n_in,
                              void* d_out, int out_size, void* d_ws, size_t ws_size,
                              hipStream_t stream)
{
  const float* x   = (const float*)d_in[0];
  const float* Wf  = (const float*)d_in[1];
  const float* bfp = (const float*)d_in[2];
  const float* Wg  = (const float*)d_in[3];
  const float* bgp = (const float*)d_in[4];
  const float* Wh  = (const float*)d_in[5];
  const float* bhp = (const float*)d_in[6];
  const float* gam = (const float*)d_in[7];
  float* out = (float*)d_out;

  char* ws = (char*)d_ws;
  u16*   xT   = (u16*)(ws);                  // 8,388,608 B  f16 [4][4096][256]
  u16*   Wall = (u16*)(ws + 8388608);        //   163,840 B  f16 [320][256]
  float* ball = (float*)(ws + 8552448);      //     2,048 B  f32 [320]
  u16*   q    = (u16*)(ws + 8554496);        // 2,097,152 B  f16 [4][4096][32]  (g, *log2e)
  u16*   km   = (u16*)(ws + 10651648);       // 2,097,152 B  f16 [4][4096][32]  (f)
  u16*   hbf  = (u16*)(ws + 12748800);       // 8,388,608 B  bf16 [4][256][4096] (h)

  k_prep<<<dim3(1104), dim3(256), 0, stream>>>(x, Wf, bfp, Wg, bgp, Wh, bhp, xT, Wall, ball);
  k_proj<<<dim3(1280), dim3(256), 0, stream>>>(xT, Wall, ball, q, km, hbf);
  k_attn<<<dim3(256),  dim3(512), 0, stream>>>(q, km, hbf, x, gam, out);
}

// Round 5
// 132.959 us; speedup vs baseline: 2.1705x; 1.0290x over previous
//
#include <hip/hip_runtime.h>
#include <hip/hip_bf16.h>
#include <hip/hip_fp16.h>

typedef __attribute__((ext_vector_type(8))) short short8;     // bf16x8 frag
typedef __attribute__((ext_vector_type(8))) _Float16 half8;   // f16x8 frag
typedef __attribute__((ext_vector_type(4))) float f32x4;
typedef __attribute__((ext_vector_type(16))) float f32x16;
typedef __attribute__((ext_vector_type(4))) unsigned int uint4v;
typedef unsigned short u16;
typedef unsigned int u32;

#define LOG2E 1.44269504088896f

typedef const void __attribute__((address_space(1))) gvoid;
typedef void __attribute__((address_space(3))) lvoid;

__device__ __forceinline__ void gll16(const void* g, void* l) {
  __builtin_amdgcn_global_load_lds((gvoid*)g, (lvoid*)l, 16, 0, 0);
}

__device__ __forceinline__ u16 f2bf(float f) {
  u32 u = __builtin_bit_cast(u32, f);
  u += 0x7fffu + ((u >> 16) & 1u);
  return (u16)(u >> 16);
}
__device__ __forceinline__ u16 f2h(float f) {
  _Float16 h = (_Float16)f;
  return __builtin_bit_cast(u16, h);
}
__device__ __forceinline__ u32 cvtpk_bf16(float lo, float hi) {
  u32 r;
  asm("v_cvt_pk_bf16_f32 %0, %1, %2" : "=v"(r) : "v"(lo), "v"(hi));
  return r;
}

// ---------------------------------------------------------------------------
// K0: prep. xT[b][n][c] (f16) from x[b][c][n] (f32); W_all f16 [320][256]
// (rows 0-31 Wf, 32-63 Wg*LOG2E, 64-319 Wh); b_all f32 [320] (bg*LOG2E).
// ---------------------------------------------------------------------------
__global__ void k_prep(const float* __restrict__ x,
                       const float* __restrict__ Wf, const float* __restrict__ bfp,
                       const float* __restrict__ Wg, const float* __restrict__ bgp,
                       const float* __restrict__ Wh, const float* __restrict__ bhp,
                       u16* __restrict__ xT, u16* __restrict__ Wall,
                       float* __restrict__ ball)
{
  int bid = blockIdx.x, t = threadIdx.x;
  if (bid < 1024) {
    __shared__ u16 tile[64][68];
    int b = bid >> 8, c0 = ((bid >> 6) & 3) << 6, n0 = (bid & 63) << 6;
#pragma unroll
    for (int r = 0; r < 4; ++r) {
      int cl = (t >> 4) + r * 16, nl = (t & 15) * 4;
      const float4 v = *(const float4*)&x[(size_t)(b * 256 + c0 + cl) * 4096 + n0 + nl];
      tile[cl][nl + 0] = f2h(v.x); tile[cl][nl + 1] = f2h(v.y);
      tile[cl][nl + 2] = f2h(v.z); tile[cl][nl + 3] = f2h(v.w);
    }
    __syncthreads();
#pragma unroll
    for (int r = 0; r < 4; ++r) {
      int nl = (t >> 4) + r * 16, cl = (t & 15) * 4;
      ushort4 o;
      o.x = tile[cl + 0][nl]; o.y = tile[cl + 1][nl];
      o.z = tile[cl + 2][nl]; o.w = tile[cl + 3][nl];
      *(ushort4*)&xT[(size_t)(b * 4096 + n0 + nl) * 256 + c0 + cl] = o;
    }
  } else {
    int wb = bid - 1024;                 // 0..79
    int e = wb * 1024 + t * 4;           // element in W_all (320*256)
    int r = e >> 8;
    const float* src = (r < 32) ? (Wf + e)
                     : (r < 64) ? (Wg + e - 32 * 256)
                                : (Wh + e - 64 * 256);
    float4 v = *(const float4*)src;
    float sc = (r >= 32 && r < 64) ? LOG2E : 1.0f;   // pre-scale Q path
    ushort4 o;
    o.x = f2h(v.x * sc); o.y = f2h(v.y * sc);
    o.z = f2h(v.z * sc); o.w = f2h(v.w * sc);
    *(ushort4*)&Wall[e] = o;
    if (wb == 0 && t < 80) {
#pragma unroll
      for (int i = 0; i < 4; ++i) {
        int idx = t * 4 + i;
        ball[idx] = (idx < 32) ? bfp[idx]
                  : (idx < 64) ? bgp[idx - 32] * LOG2E
                               : bhp[idx - 64];
      }
    }
  }
}

// ---------------------------------------------------------------------------
// K1: projections via f16 MFMA (unchanged).
// ---------------------------------------------------------------------------
__global__ __launch_bounds__(256, 4)
void k_proj(const u16* __restrict__ xT, const u16* __restrict__ Wall,
            const float* __restrict__ ball,
            u16* __restrict__ q, u16* __restrict__ kmat, u16* __restrict__ hbf)
{
  int bid = blockIdx.x, t = threadIdx.x;
  int w = t >> 6, l = t & 63, lg = l >> 4, li = l & 15;
  f32x4 Z = {0.f, 0.f, 0.f, 0.f};
  if (bid < 256) {        // ---- FG ----
    int b = bid >> 6, n0 = (bid & 63) << 6;
    int rbase = w * 16;
    half8 aw[8];
#pragma unroll
    for (int kk = 0; kk < 8; ++kk)
      aw[kk] = *(const half8*)&Wall[(rbase + li) * 256 + kk * 32 + lg * 8];
    float bias[4];
#pragma unroll
    for (int j = 0; j < 4; ++j) bias[j] = ball[rbase + 4 * lg + j];
#pragma unroll
    for (int nn = 0; nn < 4; ++nn) {
      int n = n0 + nn * 16 + li;
      f32x4 acc = Z;
#pragma unroll
      for (int kk = 0; kk < 8; ++kk) {
        half8 bx = *(const half8*)&xT[(size_t)(b * 4096 + n) * 256 + kk * 32 + lg * 8];
        acc = __builtin_amdgcn_mfma_f32_16x16x32_f16(aw[kk], bx, acc, 0, 0, 0);
      }
      ushort4 o;
      o.x = f2h(acc[0] + bias[0]); o.y = f2h(acc[1] + bias[1]);
      o.z = f2h(acc[2] + bias[2]); o.w = f2h(acc[3] + bias[3]);
      u16* dst = (rbase < 32)
               ? (kmat + (size_t)(b * 4096 + n) * 32 + rbase + 4 * lg)
               : (q    + (size_t)(b * 4096 + n) * 32 + (rbase - 32) + 4 * lg);
      *(ushort4*)dst = o;
    }
  } else {                // ---- H ----
    int hb = bid - 256;
    int b = hb >> 8, rt = (hb >> 6) & 3, n0 = (hb & 63) << 6;
    int r0 = 64 + rt * 64;
    int nbase = n0 + w * 16;
    half8 ax[8];
#pragma unroll
    for (int kk = 0; kk < 8; ++kk)
      ax[kk] = *(const half8*)&xT[(size_t)(b * 4096 + nbase + li) * 256 + kk * 32 + lg * 8];
#pragma unroll
    for (int rr = 0; rr < 4; ++rr) {
      int r = r0 + rr * 16 + li;
      f32x4 acc = Z;
#pragma unroll
      for (int kk = 0; kk < 8; ++kk) {
        half8 bw = *(const half8*)&Wall[r * 256 + kk * 32 + lg * 8];
        acc = __builtin_amdgcn_mfma_f32_16x16x32_f16(ax[kk], bw, acc, 0, 0, 0);
      }
      float bias = ball[r];
      ushort4 o;
      o.x = f2bf(acc[0] + bias); o.y = f2bf(acc[1] + bias);
      o.z = f2bf(acc[2] + bias); o.w = f2bf(acc[3] + bias);
      *(ushort4*)&hbf[(size_t)(b * 256 + r - 64) * 4096 + nbase + 4 * lg] = o;
    }
  }
}

// ---------------------------------------------------------------------------
// K2 v5: LDS-staged swapped-S attention, 2-blocks/CU residency.
//  M=32 q-rows per block, 512 blocks, 4 waves = ch(4): each wave owns a
//  64-channel V slice (V-read dup = 1). All waves compute the same S
//  (32q x 32keys) redundantly. 128 steps of 32 keys, dbuf V+K in LDS,
//  staging/read swizzles verbatim from R3 (proven). acc = 32 AGPR/wave,
//  launch_bounds(256,4) -> reg cap 128 -> 16 waves/CU.
// ---------------------------------------------------------------------------
__global__ __launch_bounds__(256, 4)
void k_attn(const u16* __restrict__ q, const u16* __restrict__ kmat,
            const u16* __restrict__ hbf, const float* __restrict__ xin,
            const float* __restrict__ gam, float* __restrict__ out)
{
  __shared__ __align__(16) char raw[36992];
  // V: [0,32768)      = [buf2][c256][32 u16]
  // K: [32768,36864)  = [buf2][row32][32 u16]
  // invL: [36864,36992)
  float* invL = (float*)(raw + 36864);

  int bid = blockIdx.x, t = threadIdx.x;
  int xcd = bid & 7;
  int b = xcd >> 1;                          // batch pinned to 2 XCDs
  int mg = ((xcd & 1) << 6) | (bid >> 3);    // 0..127
  int m0 = mg << 5;
  int w = t >> 6, l = t & 63, l31 = l & 31, hi = l >> 5;
  int c0 = w * 64;                           // wave's channel slice
  int wq = t & ~63;                          // wave base thread

  const u16* qb = q + (size_t)b * 4096 * 32;
  const u16* kb = kmat + (size_t)b * 4096 * 32;
  const u16* hb = hbf + (size_t)b * 256 * 4096;

  half8 qf0 = *(const half8*)&qb[(m0 + l31) * 32 + hi * 8];
  half8 qf1 = *(const half8*)&qb[(m0 + l31) * 32 + 16 + hi * 8];

  f32x16 Z16 = {0,0,0,0,0,0,0,0,0,0,0,0,0,0,0,0};
  f32x16 acc0 = Z16, acc1 = Z16;
  float vsum = 0.f;

  // prologue: stage tile 0 into buf 0
  {
#pragma unroll
    for (int i = 0; i < 4; ++i) {
      int u = i * 256 + t;                   // 0..1023 V granules
      int sc = u >> 2, qp = u & 3;
      int qg = qp ^ ((sc >> 1) & 3);
      const u16* src = hb + (size_t)sc * 4096 + 0 + qg * 8;
      char* dst = raw + (i * 256 + wq) * 16;
      gll16(src, dst);
    }
    if (t < 128) {                           // 128 K granules
      int row = t >> 2, qp = t & 3;
      int qg = qp ^ (row & 3);
      const u16* src = kb + (size_t)(0 + row) * 32 + qg * 8;
      char* dst = raw + 32768 + wq * 16;
      gll16(src, dst);
    }
  }

  for (int it = 0; it < 128; ++it) {
    int buf = it & 1;
    __syncthreads();          // drains vmcnt(0): cur tile staged; prev reads done

    // ---- stage NEXT tile into buf^1 (lands during this step's compute) ----
    if (it < 127) {
      int ntn = (it + 1) * 32;
      int bufn = buf ^ 1;
#pragma unroll
      for (int i = 0; i < 4; ++i) {
        int u = i * 256 + t;
        int sc = u >> 2, qp = u & 3;
        int qg = qp ^ ((sc >> 1) & 3);
        const u16* src = hb + (size_t)sc * 4096 + ntn + qg * 8;
        char* dst = raw + bufn * 16384 + (i * 256 + wq) * 16;
        gll16(src, dst);
      }
      if (t < 128) {
        int row = t >> 2, qp = t & 3;
        int qg = qp ^ (row & 3);
        const u16* src = kb + (size_t)(ntn + row) * 32 + qg * 8;
        char* dst = raw + 32768 + bufn * 2048 + wq * 16;
        gll16(src, dst);
      }
    }

    // ---- K frags from LDS (chunk swizzle ^ (row&3)) ----
    const char* kr = raw + 32768 + buf * 2048 + l31 * 64;
    int sk = (l31 & 3) * 16;
    half8 k0 = *(const half8*)(kr + ((hi * 16) ^ sk));
    half8 k1 = *(const half8*)(kr + ((32 + hi * 16) ^ sk));

    // ---- S = K * Q (swapped): lane holds P[n-rows][m = l31] ----
    f32x16 sa = __builtin_amdgcn_mfma_f32_32x32x16_f16(k0, qf0, Z16, 0, 0, 0);
    sa = __builtin_amdgcn_mfma_f32_32x32x16_f16(k1, qf1, sa, 0, 0, 0);

    // ---- V frags from LDS (8B slot swizzle ^ ((c>>1)&3)<<1) ----
    const char* vbase = raw + buf * 16384;
    uint2 a0, a1;
    uint4v v00, v01, v10, v11;
    {
      const char* vr = vbase + (c0 + 0 + l31) * 64;
      int sv = (((c0 + 0 + l31) >> 1) & 3) << 1;
      a0 = *(const uint2*)(vr + ((0 + hi) ^ sv) * 8);
      a1 = *(const uint2*)(vr + ((2 + hi) ^ sv) * 8);
      v00 = (uint4v){a0.x, a0.y, a1.x, a1.y};
      a0 = *(const uint2*)(vr + ((4 + hi) ^ sv) * 8);
      a1 = *(const uint2*)(vr + ((6 + hi) ^ sv) * 8);
      v01 = (uint4v){a0.x, a0.y, a1.x, a1.y};
    }
    {
      const char* vr = vbase + (c0 + 32 + l31) * 64;
      int sv = (((c0 + 32 + l31) >> 1) & 3) << 1;
      a0 = *(const uint2*)(vr + ((0 + hi) ^ sv) * 8);
      a1 = *(const uint2*)(vr + ((2 + hi) ^ sv) * 8);
      v10 = (uint4v){a0.x, a0.y, a1.x, a1.y};
      a0 = *(const uint2*)(vr + ((4 + hi) ^ sv) * 8);
      a1 = *(const uint2*)(vr + ((6 + hi) ^ sv) * 8);
      v11 = (uint4v){a0.x, a0.y, a1.x, a1.y};
    }

    // ---- exp + row-sum + pack to bf16 ----
    float p[16];
#pragma unroll
    for (int r = 0; r < 16; ++r) p[r] = __builtin_amdgcn_exp2f(sa[r]);
    float s0 = 0.f, s1 = 0.f;
#pragma unroll
    for (int r = 0; r < 16; r += 2) { s0 += p[r]; s1 += p[r + 1]; }
    vsum += s0 + s1;
    u32 pk[8];
#pragma unroll
    for (int i = 0; i < 8; ++i) pk[i] = cvtpk_bf16(p[2 * i], p[2 * i + 1]);
    uint4v pa0u = {pk[0], pk[1], pk[2], pk[3]};
    uint4v pa1u = {pk[4], pk[5], pk[6], pk[7]};
    short8 pa0 = __builtin_bit_cast(short8, pa0u);
    short8 pa1 = __builtin_bit_cast(short8, pa1u);

    // ---- PV: 4 x mfma32x32x16 bf16 ----
    __builtin_amdgcn_s_setprio(1);
    acc0 = __builtin_amdgcn_mfma_f32_32x32x16_bf16(pa0, __builtin_bit_cast(short8, v00), acc0, 0, 0, 0);
    acc0 = __builtin_amdgcn_mfma_f32_32x32x16_bf16(pa1, __builtin_bit_cast(short8, v01), acc0, 0, 0, 0);
    acc1 = __builtin_amdgcn_mfma_f32_32x32x16_bf16(pa0, __builtin_bit_cast(short8, v10), acc1, 0, 0, 0);
    acc1 = __builtin_amdgcn_mfma_f32_32x32x16_bf16(pa1, __builtin_bit_cast(short8, v11), acc1, 0, 0, 0);
    __builtin_amdgcn_s_setprio(0);
  }

  // ---- epilogue: normalize + write (all waves have identical row-sums) ----
  float vt = vsum + __shfl_xor(vsum, 32);
  if (w == 0 && l < 32) invL[l31] = 1.0f / vt;
  __syncthreads();
  {
    float gamma = gam[0];
    const float* xb = xin + (size_t)b * 256 * 4096;
    float* ob = out + (size_t)b * 256 * 4096;
    f32x16 acc[2] = {acc0, acc1};
#pragma unroll
    for (int g = 0; g < 4; ++g) {
      float4 inv4 = *(const float4*)&invL[8 * g + 4 * hi];
#pragma unroll
      for (int ct = 0; ct < 2; ++ct) {
        int c = c0 + ct * 32 + l31;
        size_t base = (size_t)c * 4096 + m0 + 8 * g + 4 * hi;
        float4 xv = *(const float4*)&xb[base];
        float4 ov;
        ov.x = gamma * acc[ct][4 * g + 0] * inv4.x + xv.x;
        ov.y = gamma * acc[ct][4 * g + 1] * inv4.y + xv.y;
        ov.z = gamma * acc[ct][4 * g + 2] * inv4.z + xv.z;
        ov.w = gamma * acc[ct][4 * g + 3] * inv4.w + xv.w;
        *(float4*)&ob[base] = ov;
      }
    }
  }
}

// ---------------------------------------------------------------------------
extern "C" void kernel_launch(void* const* d_in, const int* in_sizes, int n_in,
                              void* d_out, int out_size, void* d_ws, size_t ws_size,
                              hipStream_t stream)
{
  const float* x   = (const float*)d_in[0];
  const float* Wf  = (const float*)d_in[1];
  const float* bfp = (const float*)d_in[2];
  const float* Wg  = (const float*)d_in[3];
  const float* bgp = (const float*)d_in[4];
  const float* Wh  = (const float*)d_in[5];
  const float* bhp = (const float*)d_in[6];
  const float* gam = (const float*)d_in[7];
  float* out = (float*)d_out;

  char* ws = (char*)d_ws;
  u16*   xT   = (u16*)(ws);                  // 8,388,608 B  f16 [4][4096][256]
  u16*   Wall = (u16*)(ws + 8388608);        //   163,840 B  f16 [320][256]
  float* ball = (float*)(ws + 8552448);      //     2,048 B  f32 [320]
  u16*   q    = (u16*)(ws + 8554496);        // 2,097,152 B  f16 [4][4096][32]  (g, *log2e)
  u16*   km   = (u16*)(ws + 10651648);       // 2,097,152 B  f16 [4][4096][32]  (f)
  u16*   hbf  = (u16*)(ws + 12748800);       // 8,388,608 B  bf16 [4][256][4096] (h)

  k_prep<<<dim3(1104), dim3(256), 0, stream>>>(x, Wf, bfp, Wg, bgp, Wh, bhp, xT, Wall, ball);
  k_proj<<<dim3(1280), dim3(256), 0, stream>>>(xT, Wall, ball, q, km, hbf);
  k_attn<<<dim3(512),  dim3(256), 0, stream>>>(q, km, hbf, x, gam, out);
}